// Round 1
// baseline (505.000 us; speedup 1.0000x reference)
//
#include <hip/hip_runtime.h>

#define HW   (128*128)
#define DHW  (128*128*128)
#define NTOT (4*DHW)
#define NB_RED 2048   // blocks for grid-stride reductions

__device__ __forceinline__ float sigf(float x){ return 1.0f/(1.0f+__expf(-x)); }

// ---------- Pass 1: occupancy / surface / overhang sums in one read of v ----------
__global__ __launch_bounds__(256) void reduce_grid_k(
    const float* __restrict__ v, float* __restrict__ p_occ,
    float* __restrict__ p_surf, float* __restrict__ p_over)
{
    float occ = 0.f, surf = 0.f, over = 0.f;
    int stride = gridDim.x * blockDim.x;
    for (int i = blockIdx.x*blockDim.x + threadIdx.x; i < NTOT; i += stride) {
        int x = i & 127, y = (i>>7) & 127, z = (i>>14) & 127;
        float val = v[i];
        occ += val;
        float wz = (z==0 || z==127) ? 2.f : 3.f;
        float wy = (y==0 || y==127) ? 2.f : 3.f;
        float wx = (x==0 || x==127) ? 2.f : 3.f;
        surf += val * (wz*wy*wx);   // sum of all-ones 3^3 conv == coverage-weighted sum
        if (z >= 1) {
            const float* below = v + i - HW;
            float s = 0.f;
            #pragma unroll
            for (int dy = -1; dy <= 1; ++dy) {
                if ((unsigned)(y+dy) > 127u) continue;
                #pragma unroll
                for (int dx = -1; dx <= 1; ++dx) {
                    if ((unsigned)(x+dx) > 127u) continue;
                    s += below[dy*128 + dx];
                }
            }
            over += val * (1.f - s * (1.f/9.f));
        }
    }
    __shared__ float sm[3][4];
    #pragma unroll
    for (int o = 32; o; o >>= 1) {
        occ  += __shfl_down(occ,  o, 64);
        surf += __shfl_down(surf, o, 64);
        over += __shfl_down(over, o, 64);
    }
    int lane = threadIdx.x & 63, wid = threadIdx.x >> 6;
    if (lane == 0) { sm[0][wid]=occ; sm[1][wid]=surf; sm[2][wid]=over; }
    __syncthreads();
    if (threadIdx.x == 0) {
        p_occ [blockIdx.x] = sm[0][0]+sm[0][1]+sm[0][2]+sm[0][3];
        p_surf[blockIdx.x] = sm[1][0]+sm[1][1]+sm[1][2]+sm[1][3];
        p_over[blockIdx.x] = sm[2][0]+sm[2][1]+sm[2][2]+sm[2][3];
    }
}

// ---------- Resin-trap iteration 1: analytic from seed (no mask read) ----------
// mask0 = seed (1 at (5,5,5) per batch). c = cross-conv(seed) is 1 exactly at the
// 6-neighbors, 0 elsewhere. act = sig(20*(c-0.5)); mask1 = max(seed,act)*(1-v).
__global__ __launch_bounds__(256) void stencil_first_k(
    float* __restrict__ dst, const float* __restrict__ v)
{
    int x = threadIdx.x;
    int y = blockIdx.x * blockDim.y + threadIdx.y;
    int z = blockIdx.y;
    int b = blockIdx.z;
    int i = ((b*128 + z)*128 + y)*128 + x;
    int d = abs(z-5) + abs(y-5) + abs(x-5);
    float pre = (d == 0) ? 1.0f : ((d == 1) ? sigf(10.0f) : sigf(-10.0f));
    dst[i] = pre * (1.0f - v[i]);
}

// ---------- Generic resin-trap stencil; optionally reduces its output ----------
__global__ __launch_bounds__(256) void stencil_k(
    const float* __restrict__ src, float* __restrict__ dst,
    const float* __restrict__ v, float* __restrict__ p_trap)
{
    int x = threadIdx.x;
    int y = blockIdx.x * blockDim.y + threadIdx.y;
    int z = blockIdx.y;
    int b = blockIdx.z;
    int i = ((b*128 + z)*128 + y)*128 + x;
    float c = 0.f;
    if (x > 0)   c += src[i-1];
    if (x < 127) c += src[i+1];
    if (y > 0)   c += src[i-128];
    if (y < 127) c += src[i+128];
    if (z > 0)   c += src[i-HW];
    if (z < 127) c += src[i+HW];
    float act = sigf(20.0f*(c - 0.5f));
    float m = fmaxf(src[i], act) * (1.0f - v[i]);
    dst[i] = m;

    if (p_trap != nullptr) {
        __shared__ float sm[4];
        #pragma unroll
        for (int o = 32; o; o >>= 1) m += __shfl_down(m, o, 64);
        int tid = threadIdx.y*128 + threadIdx.x;
        int lane = tid & 63, wid = tid >> 6;
        if (lane == 0) sm[wid] = m;
        __syncthreads();
        if (tid == 0) {
            int blin = (blockIdx.z*gridDim.y + blockIdx.y)*gridDim.x + blockIdx.x;
            p_trap[blin] = sm[0] + sm[1] + sm[2] + sm[3];
        }
    }
}

// ---------- Finalize: sum partials, combine scalars ----------
__global__ __launch_bounds__(1024) void finalize_k(
    const float* __restrict__ p_occ, const float* __restrict__ p_surf,
    const float* __restrict__ p_over, const float* __restrict__ p_trap,
    int n1, int n2, float* __restrict__ out)
{
    double occ=0, surf=0, over=0, trap=0;
    for (int i = threadIdx.x; i < n1; i += blockDim.x) {
        occ += p_occ[i]; surf += p_surf[i]; over += p_over[i];
    }
    for (int i = threadIdx.x; i < n2; i += blockDim.x) trap += p_trap[i];
    __shared__ double sm[4][16];
    #pragma unroll
    for (int o = 32; o; o >>= 1) {
        occ  += __shfl_down(occ,  o, 64);
        surf += __shfl_down(surf, o, 64);
        over += __shfl_down(over, o, 64);
        trap += __shfl_down(trap, o, 64);
    }
    int lane = threadIdx.x & 63, wid = threadIdx.x >> 6;
    if (lane == 0) { sm[0][wid]=occ; sm[1][wid]=surf; sm[2][wid]=over; sm[3][wid]=trap; }
    __syncthreads();
    if (threadIdx.x == 0) {
        double so=0, ss=0, sv=0, st=0;
        int nw = blockDim.x >> 6;
        for (int w = 0; w < nw; ++w) { so+=sm[0][w]; ss+=sm[1][w]; sv+=sm[2][w]; st+=sm[3][w]; }
        double N = (double)NTOT;
        double overhang = sv / N;
        double surface_term = ss / 27.0 / N;
        double occupancy = so / N;
        double occ_pen = 10.0 * (occupancy - 0.5) * (occupancy - 0.5);
        double trap_pen = 100.0 * st / N;
        out[0] = (float)overhang;
        out[1] = (float)(surface_term - trap_pen - occ_pen);
    }
}

extern "C" void kernel_launch(void* const* d_in, const int* in_sizes, int n_in,
                              void* d_out, int out_size, void* d_ws, size_t ws_size,
                              hipStream_t stream)
{
    const float* v = (const float*)d_in[0];
    float* out = (float*)d_out;
    char* ws = (char*)d_ws;

    float* maskA  = (float*)(ws);
    float* maskB  = (float*)(ws + (size_t)NTOT*4);
    float* p_occ  = (float*)(ws + (size_t)NTOT*8);
    float* p_surf = p_occ  + NB_RED;
    float* p_over = p_surf + NB_RED;
    float* p_trap = p_over + NB_RED;          // 32768 floats
    const int NB_ST = 64*128*4;               // stencil block count

    dim3 sb(128, 2, 1);
    dim3 sg(64, 128, 4);

    reduce_grid_k<<<NB_RED, 256, 0, stream>>>(v, p_occ, p_surf, p_over);

    // iteration 1 (analytic seed) -> maskA
    stencil_first_k<<<sg, sb, 0, stream>>>(maskA, v);
    // iterations 2..10, ping-pong; last one also reduces
    float* src = maskA; float* dst = maskB;
    for (int it = 2; it <= 10; ++it) {
        float* pt = (it == 10) ? p_trap : nullptr;
        stencil_k<<<sg, sb, 0, stream>>>(src, dst, v, pt);
        float* t = src; src = dst; dst = t;
    }

    finalize_k<<<1, 1024, 0, stream>>>(p_occ, p_surf, p_over, p_trap,
                                       NB_RED, NB_ST, out);
}

// Round 2
// 250.943 us; speedup vs baseline: 2.0124x; 2.0124x over previous
//
#include <hip/hip_runtime.h>

#define HW    (128*128)
#define DHW   (128*128*128)
#define NTOT  (4*DHW)
#define ZCH   8            // z-chunk per stencil block
#define NB_A  (16*128*4)   // kernel A block count (y-blocks * z * batch)
#define NB_ST (16*16*4)    // stencil block count (y-blocks * z-chunks * batch)

__device__ __forceinline__ float sigf(float x){ return 1.0f/(1.0f+__expf(-x)); }
__device__ __forceinline__ float4 ld4(const float* p){ return *(const float4*)p; }
__device__ __forceinline__ void st4(float* p, float4 q){ *(float4*)p = q; }

// ---------------------------------------------------------------------------
// Kernel A (fused): occupancy/surface/overhang partial sums + analytic
// resin-trap iteration 1 (mask1 = pre(d)*(1-v)), one read of v.
// block (32,8): thread = x-quad [4tx,4tx+3], y = blockIdx.x*8+ty, z = blockIdx.y
// ---------------------------------------------------------------------------
__global__ __launch_bounds__(256) void fused_first_k(
    const float* __restrict__ v, float* __restrict__ mask1,
    float* __restrict__ p_occ, float* __restrict__ p_surf,
    float* __restrict__ p_over)
{
    const int tx = threadIdx.x, ty = threadIdx.y;
    const int y = blockIdx.x*8 + ty;
    const int z = blockIdx.y;
    const int b = blockIdx.z;
    const int x4 = tx*4;
    const size_t base = (size_t)b*DHW;
    const size_t idx = base + ((size_t)z*128 + y)*128 + x4;

    float4 val = ld4(v + idx);

    // occupancy
    float occ = val.x + val.y + val.z + val.w;

    // surface: all-ones 3^3 conv total == coverage-weighted sum (2 at faces, 3 interior)
    float wz = (z==0 || z==127) ? 2.f : 3.f;
    float wy = (y==0 || y==127) ? 2.f : 3.f;
    float wx0 = (x4==0)     ? 2.f : 3.f;
    float wx3 = (x4+3==127) ? 2.f : 3.f;
    float surf = wz*wy*(wx0*val.x + 3.f*val.y + 3.f*val.z + wx3*val.w);

    // overhang: curr * (1 - (3x3 sum of below)/9), z>=1
    float over = 0.f;
    if (z >= 1) {
        float4 s = make_float4(0,0,0,0);
        const float* below = v + idx - HW;
        #pragma unroll
        for (int dy = -1; dy <= 1; ++dy) {
            if ((unsigned)(y+dy) > 127u) continue;
            const float* row = below + dy*128;
            float4 q = ld4(row);
            float ql = (tx>0)  ? row[-1] : 0.f;
            float qr = (tx<31) ? row[4]  : 0.f;
            s.x += ql  + q.x + q.y;
            s.y += q.x + q.y + q.z;
            s.z += q.y + q.z + q.w;
            s.w += q.z + q.w + qr;
        }
        const float inv9 = 1.f/9.f;
        over = val.x*(1.f - s.x*inv9) + val.y*(1.f - s.y*inv9)
             + val.z*(1.f - s.z*inv9) + val.w*(1.f - s.w*inv9);
    }

    // resin-trap iteration 1, analytic from seed at (5,5,5):
    // d==0 -> 1, d==1 -> sig(10), else sig(-10); times (1-v)
    const float a_hi = sigf(10.0f), a_lo = sigf(-10.0f);
    int dzy = abs(z-5) + abs(y-5);
    float4 m;
    {
        int d0 = dzy + abs(x4+0-5);
        int d1 = dzy + abs(x4+1-5);
        int d2 = dzy + abs(x4+2-5);
        int d3 = dzy + abs(x4+3-5);
        float p0 = (d0==0)?1.f:((d0==1)?a_hi:a_lo);
        float p1 = (d1==0)?1.f:((d1==1)?a_hi:a_lo);
        float p2 = (d2==0)?1.f:((d2==1)?a_hi:a_lo);
        float p3 = (d3==0)?1.f:((d3==1)?a_hi:a_lo);
        m = make_float4(p0*(1.f-val.x), p1*(1.f-val.y), p2*(1.f-val.z), p3*(1.f-val.w));
    }
    st4(mask1 + idx, m);

    // block reduce 3 sums
    __shared__ float sm[3][4];
    #pragma unroll
    for (int o = 32; o; o >>= 1) {
        occ  += __shfl_down(occ,  o, 64);
        surf += __shfl_down(surf, o, 64);
        over += __shfl_down(over, o, 64);
    }
    int tid = ty*32 + tx, lane = tid & 63, wid = tid >> 6;
    if (lane == 0) { sm[0][wid]=occ; sm[1][wid]=surf; sm[2][wid]=over; }
    __syncthreads();
    if (tid == 0) {
        int blin = (b*gridDim.y + blockIdx.y)*gridDim.x + blockIdx.x;
        p_occ [blin] = sm[0][0]+sm[0][1]+sm[0][2]+sm[0][3];
        p_surf[blin] = sm[1][0]+sm[1][1]+sm[1][2]+sm[1][3];
        p_over[blin] = sm[2][0]+sm[2][1]+sm[2][2]+sm[2][3];
    }
}

// ---------------------------------------------------------------------------
// Resin-trap stencil, z-march: thread owns an x-quad column over ZCH z-steps.
// Keeps center planes z-1,z,z+1 in registers (one new plane load per step).
// If p_trap != null: last iteration — accumulate sum, skip dst write.
// block (32,8); grid (16 y-blocks, 128/ZCH z-chunks, 4 batches)
// ---------------------------------------------------------------------------
__global__ __launch_bounds__(256) void stencil_march_k(
    const float* __restrict__ src, float* __restrict__ dst,
    const float* __restrict__ v, float* __restrict__ p_trap)
{
    const int tx = threadIdx.x, ty = threadIdx.y;
    const int y  = blockIdx.x*8 + ty;
    const int z0 = blockIdx.y*ZCH;
    const int b  = blockIdx.z;
    const int x4 = tx*4;
    const size_t base = (size_t)b*DHW + (size_t)y*128 + x4;
    // addr of (z, y, x4) = base + z*HW

    const float4 zero = make_float4(0,0,0,0);
    float4 cm = (z0 > 0) ? ld4(src + base + (size_t)(z0-1)*HW) : zero;
    float4 cc = ld4(src + base + (size_t)z0*HW);

    float trap = 0.f;
    const bool reduce_mode = (p_trap != nullptr);

    for (int z = z0; z < z0 + ZCH; ++z) {
        const size_t izz = base + (size_t)z*HW;
        float4 cp = (z < 127) ? ld4(src + izz + HW) : zero;
        float4 ym = (y > 0)   ? ld4(src + izz - 128) : zero;
        float4 yp = (y < 127) ? ld4(src + izz + 128) : zero;
        float  xl = (tx > 0)  ? src[izz - 1] : 0.f;
        float  xr = (tx < 31) ? src[izz + 4] : 0.f;
        float4 vv = ld4(v + izz);

        float c0 = xl   + cc.y + ym.x + yp.x + cm.x + cp.x;
        float c1 = cc.x + cc.z + ym.y + yp.y + cm.y + cp.y;
        float c2 = cc.y + cc.w + ym.z + yp.z + cm.z + cp.z;
        float c3 = cc.z + xr   + ym.w + yp.w + cm.w + cp.w;

        float4 m;
        m.x = fmaxf(cc.x, sigf(20.f*c0 - 10.f)) * (1.f - vv.x);
        m.y = fmaxf(cc.y, sigf(20.f*c1 - 10.f)) * (1.f - vv.y);
        m.z = fmaxf(cc.z, sigf(20.f*c2 - 10.f)) * (1.f - vv.z);
        m.w = fmaxf(cc.w, sigf(20.f*c3 - 10.f)) * (1.f - vv.w);

        if (reduce_mode) {
            trap += m.x + m.y + m.z + m.w;
        } else {
            st4(dst + izz, m);
        }
        cm = cc; cc = cp;
    }

    if (reduce_mode) {
        __shared__ float sm[4];
        #pragma unroll
        for (int o = 32; o; o >>= 1) trap += __shfl_down(trap, o, 64);
        int tid = ty*32 + tx, lane = tid & 63, wid = tid >> 6;
        if (lane == 0) sm[wid] = trap;
        __syncthreads();
        if (tid == 0) {
            int blin = (b*gridDim.y + blockIdx.y)*gridDim.x + blockIdx.x;
            p_trap[blin] = sm[0] + sm[1] + sm[2] + sm[3];
        }
    }
}

// ---------------------------------------------------------------------------
// Finalize: sum partials (f64), combine scalars
// ---------------------------------------------------------------------------
__global__ __launch_bounds__(1024) void finalize_k(
    const float* __restrict__ p_occ, const float* __restrict__ p_surf,
    const float* __restrict__ p_over, const float* __restrict__ p_trap,
    int n1, int n2, float* __restrict__ out)
{
    double occ=0, surf=0, over=0, trap=0;
    for (int i = threadIdx.x; i < n1; i += blockDim.x) {
        occ += p_occ[i]; surf += p_surf[i]; over += p_over[i];
    }
    for (int i = threadIdx.x; i < n2; i += blockDim.x) trap += p_trap[i];
    __shared__ double sm[4][16];
    #pragma unroll
    for (int o = 32; o; o >>= 1) {
        occ  += __shfl_down(occ,  o, 64);
        surf += __shfl_down(surf, o, 64);
        over += __shfl_down(over, o, 64);
        trap += __shfl_down(trap, o, 64);
    }
    int lane = threadIdx.x & 63, wid = threadIdx.x >> 6;
    if (lane == 0) { sm[0][wid]=occ; sm[1][wid]=surf; sm[2][wid]=over; sm[3][wid]=trap; }
    __syncthreads();
    if (threadIdx.x == 0) {
        double so=0, ss=0, sv=0, st=0;
        int nw = blockDim.x >> 6;
        for (int w = 0; w < nw; ++w) { so+=sm[0][w]; ss+=sm[1][w]; sv+=sm[2][w]; st+=sm[3][w]; }
        double N = (double)NTOT;
        double overhang = sv / N;
        double surface_term = ss / 27.0 / N;
        double occupancy = so / N;
        double occ_pen = 10.0 * (occupancy - 0.5) * (occupancy - 0.5);
        double trap_pen = 100.0 * st / N;
        out[0] = (float)overhang;
        out[1] = (float)(surface_term - trap_pen - occ_pen);
    }
}

extern "C" void kernel_launch(void* const* d_in, const int* in_sizes, int n_in,
                              void* d_out, int out_size, void* d_ws, size_t ws_size,
                              hipStream_t stream)
{
    const float* v = (const float*)d_in[0];
    float* out = (float*)d_out;
    char* ws = (char*)d_ws;

    float* maskA  = (float*)(ws);
    float* maskB  = (float*)(ws + (size_t)NTOT*4);
    float* p_occ  = (float*)(ws + (size_t)NTOT*8);
    float* p_surf = p_occ  + NB_A;
    float* p_over = p_surf + NB_A;
    float* p_trap = p_over + NB_A;

    dim3 blk(32, 8, 1);
    dim3 grdA(16, 128, 4);
    dim3 grdS(16, 128/ZCH, 4);

    // pass 1: reductions + analytic iteration-1 mask, one read of v
    fused_first_k<<<grdA, blk, 0, stream>>>(v, maskA, p_occ, p_surf, p_over);

    // iterations 2..10, ping-pong; iteration 10 reduces only (no write)
    float* src = maskA; float* dst = maskB;
    for (int it = 2; it <= 10; ++it) {
        float* pt = (it == 10) ? p_trap : nullptr;
        stencil_march_k<<<grdS, blk, 0, stream>>>(src, dst, v, pt);
        float* t = src; src = dst; dst = t;
    }

    finalize_k<<<1, 1024, 0, stream>>>(p_occ, p_surf, p_over, p_trap,
                                       NB_A, NB_ST, out);
}